// Round 6
// baseline (387.571 us; speedup 1.0000x reference)
//
#include <hip/hip_runtime.h>
#include <hip/hip_bf16.h>
#include <hip/hip_cooperative_groups.h>

#define NN 1024   // nodes
#define HD 128    // hidden dim
#define NE 32768  // edges
#define CAP 128   // per-row neighbor capacity (Poisson(32): P(>127) ~ 1e-40)

namespace cg = cooperative_groups;
using bf16 = __hip_bfloat16;
static __device__ __forceinline__ float b2f(bf16 v) { return __bfloat162float(v); }

struct Args {
    const unsigned short* xraw;
    const int* ei;
    const void* src[13];
    float* dst[13];
    int n[13];
    float* At;   // [128][128] = dp_w1[:, :128]^T
    float* Bt;   // [128][128] = dp_w1[:, 128:]^T
    int* deg;
    int* col;
    float* yA;
    float* yB;
    float* u;
    float* v;
    void* out;
};

// Single cooperative kernel: convert -> (mm0 + edge fill) -> layer -> layer
// -> final -> pairwise, separated by grid.sync().
__global__ __launch_bounds__(256) void k_all(Args a) {
    cg::grid_group grid = cg::this_grid();
    __shared__ __align__(16) float smem[9376];  // 37504 B, overlaid per phase
    __shared__ int swild;

    int t = threadIdx.x;
    int b = blockIdx.x;
    int gid = b * 256 + t, gsz = gridDim.x * 256;   // 512*256 = 131072

    // per-block dtype detect (no cross-block dependency).
    // fp32 read as uint16 stream has wild bf16-exponent halves; bf16 N(0,s) doesn't.
    if (t == 0) swild = 0;
    __syncthreads();
    { int e = (a.xraw[t] >> 7) & 0xFF; if (e < 97 || e > 157) atomicAdd(&swild, 1); }
    __syncthreads();
    const int f = (swild > 32) ? 1 : 0;

    // ---- Phase A: zero deg + convert all float tensors (+ dp_w1 transpose) ----
    for (int i = gid; i < NN; i += gsz) a.deg[i] = 0;
#pragma unroll 1
    for (int tn = 0; tn < 13; tn++) {
        int n = a.n[tn];
        for (int i = gid; i < n; i += gsz) {
            float v = f ? ((const float*)a.src[tn])[i] : b2f(((const bf16*)a.src[tn])[i]);
            if (tn == 9) {  // dp_w1 [128][256] -> transposed halves
                int hh = i >> 8, kk = i & 255;
                if (kk < HD) a.At[kk * HD + hh] = v;
                else         a.Bt[(kk - HD) * HD + hh] = v;
            } else {
                a.dst[tn][i] = v;
            }
        }
    }
    grid.sync();

    const int half = t >> 7, h = t & 127;
    const int n0 = b * 2 + half;   // node owned by this half-block

    // ---- Phase B: yA = x @ W0 (raw) + edge fill ----
    {
        float* rows = smem;  // [2][128]
        rows[half * HD + h] = a.dst[0][n0 * HD + h];
        __syncthreads();
        float acc = 0.f;
        const float* W = a.dst[1];
#pragma unroll 8
        for (int k = 0; k < HD; k++) acc += rows[half * HD + k] * W[k * HD + h];
        a.yA[n0 * HD + h] = acc;
        for (int e = gid; e < NE; e += gsz) {
            int dst = a.ei[NE + e];
            int slot = atomicAdd(&a.deg[dst], 1);
            if (slot < CAP) a.col[dst * CAP + slot] = a.ei[e];
        }
    }
    grid.sync();

    // ---- Phases C, D: GCN layers (gather -> norm+bias -> relu -> matmul) ----
    auto layer = [&](const float* yin, float* yout, const float* bias, const float* W) {
        float* hrow = smem;  // [2][128]
        int cnt = a.deg[n0];
        float dvn = rsqrtf((float)cnt + 1.f);
        float s = dvn * yin[n0 * HD + h];
        const int* cp = a.col + n0 * CAP;
        for (int i = 0; i < cnt; i++) {
            int c = cp[i];
            s += rsqrtf((float)a.deg[c] + 1.f) * yin[c * HD + h];
        }
        float hv = dvn * s + bias[h];
        hrow[half * HD + h] = fmaxf(hv, 0.f);
        __syncthreads();
        float acc = 0.f;
#pragma unroll 8
        for (int k = 0; k < HD; k++) acc += hrow[half * HD + k] * W[k * HD + h];
        yout[n0 * HD + h] = acc;
    };
    layer(a.yA, a.yB, a.dst[2], a.dst[3]);
    grid.sync();
    layer(a.yB, a.yA, a.dst[4], a.dst[5]);
    grid.sync();

    // ---- Phase E: gather -> h2 -> emb (store) -> u,v projections ----
    {
        float* h2row  = smem;        // [2][128]
        float* embrow = smem + 256;  // [2][128]
        int cnt = a.deg[n0];
        float dvn = rsqrtf((float)cnt + 1.f);
        float s = dvn * a.yA[n0 * HD + h];
        const int* cp = a.col + n0 * CAP;
        for (int i = 0; i < cnt; i++) {
            int c = cp[i];
            s += rsqrtf((float)a.deg[c] + 1.f) * a.yA[c * HD + h];
        }
        h2row[half * HD + h] = dvn * s + a.dst[6][h];  // conv2 bias, no relu
        __syncthreads();
        float acc = a.dst[8][h];                       // out_b
#pragma unroll 8
        for (int k = 0; k < HD; k++) acc += h2row[half * HD + k] * a.dst[7][k * HD + h];
        embrow[half * HD + h] = acc;
        if (f) ((float*)a.out)[n0 * HD + h] = acc;
        else   ((bf16*)a.out)[n0 * HD + h] = __float2bfloat16(acc);
        __syncthreads();
        float uu = a.dst[10][h], vv = 0.f;  // fold dp_b1 into u
#pragma unroll 8
        for (int k = 0; k < HD; k++) {
            float e = embrow[half * HD + k];
            uu += e * a.At[k * HD + h];
            vv += e * a.Bt[k * HD + h];
        }
        a.u[n0 * HD + h] = uu;
        a.v[n0 * HD + h] = vv;
    }
    grid.sync();

    // ---- Phase F: pairwise upper-triangle 32x32 tiles, mirrored writes ----
    {
        float4* su4  = (float4*)smem;            // 1024 float4
        float4* sv4  = (float4*)(smem + 4096);   // 1024 float4
        float4* sw24 = (float4*)(smem + 8192);   // 32 float4
        float*  sp   = smem + 8320;              // [32][33]
        float* df = (float*)a.out + (size_t)NN * HD;
        bf16*  db = (bf16*)a.out + (size_t)NN * HD;
        auto ST = [&](size_t idx, float val) {
            if (f) df[idx] = val;
            else   db[idx] = __float2bfloat16(val);
        };
        float bb2 = a.dst[12][0];
        const float* w2 = a.dst[11];

        for (int tile = b; tile < 528; tile += gridDim.x) {
            int rem = tile, bi = 0;
            while (rem >= 32 - bi) { rem -= 32 - bi; bi++; }
            int bj = bi + rem;
            int i0 = bi * 32, j0 = bj * 32;

#pragma unroll
            for (int r = 0; r < 4; r++) {
                int pidx = t + r * 256;
                int rowp = pidx >> 5, c = pidx & 31;
                su4[pidx] = *(const float4*)(a.u + (size_t)(i0 + rowp) * HD + (c << 2));
                sv4[c * 32 + rowp] = *(const float4*)(a.v + (size_t)(j0 + rowp) * HD + (c << 2));
            }
            if (t < 32) sw24[t] = *(const float4*)(w2 + 4 * t);
            __syncthreads();

            int jl = t & 31, ib = t >> 5;
            float acc0 = 0.f, acc1 = 0.f, acc2 = 0.f, acc3 = 0.f;
            for (int c = 0; c < 32; c++) {
                float4 vv = sv4[c * 32 + jl];
                float4 w4 = sw24[c];
                float4 a0 = su4[(ib * 4 + 0) * 32 + c];
                float4 a1 = su4[(ib * 4 + 1) * 32 + c];
                float4 a2 = su4[(ib * 4 + 2) * 32 + c];
                float4 a3 = su4[(ib * 4 + 3) * 32 + c];
                acc0 += fmaxf(a0.x + vv.x, 0.f) * w4.x + fmaxf(a0.y + vv.y, 0.f) * w4.y +
                        fmaxf(a0.z + vv.z, 0.f) * w4.z + fmaxf(a0.w + vv.w, 0.f) * w4.w;
                acc1 += fmaxf(a1.x + vv.x, 0.f) * w4.x + fmaxf(a1.y + vv.y, 0.f) * w4.y +
                        fmaxf(a1.z + vv.z, 0.f) * w4.z + fmaxf(a1.w + vv.w, 0.f) * w4.w;
                acc2 += fmaxf(a2.x + vv.x, 0.f) * w4.x + fmaxf(a2.y + vv.y, 0.f) * w4.y +
                        fmaxf(a2.z + vv.z, 0.f) * w4.z + fmaxf(a2.w + vv.w, 0.f) * w4.w;
                acc3 += fmaxf(a3.x + vv.x, 0.f) * w4.x + fmaxf(a3.y + vv.y, 0.f) * w4.y +
                        fmaxf(a3.z + vv.z, 0.f) * w4.z + fmaxf(a3.w + vv.w, 0.f) * w4.w;
            }
            float pr0 = 1.f / (1.f + __expf(-(acc0 + bb2)));
            float pr1 = 1.f / (1.f + __expf(-(acc1 + bb2)));
            float pr2 = 1.f / (1.f + __expf(-(acc2 + bb2)));
            float pr3 = 1.f / (1.f + __expf(-(acc3 + bb2)));
            sp[(ib * 4 + 0) * 33 + jl] = pr0;
            sp[(ib * 4 + 1) * 33 + jl] = pr1;
            sp[(ib * 4 + 2) * 33 + jl] = pr2;
            sp[(ib * 4 + 3) * 33 + jl] = pr3;
            __syncthreads();

            if (bi < bj) {
                ST((size_t)(i0 + ib * 4 + 0) * NN + j0 + jl, pr0);
                ST((size_t)(i0 + ib * 4 + 1) * NN + j0 + jl, pr1);
                ST((size_t)(i0 + ib * 4 + 2) * NN + j0 + jl, pr2);
                ST((size_t)(i0 + ib * 4 + 3) * NN + j0 + jl, pr3);
#pragma unroll
                for (int pq = 0; pq < 4; pq++) {
                    int jrow = ib * 4 + pq;
                    ST((size_t)(j0 + jrow) * NN + i0 + jl, sp[jl * 33 + jrow]);
                }
            } else {
#pragma unroll
                for (int pq = 0; pq < 4; pq++) {
                    int il = ib * 4 + pq;
                    float val = (il < jl) ? sp[il * 33 + jl]
                              : ((il > jl) ? sp[jl * 33 + il] : 0.f);
                    ST((size_t)(i0 + il) * NN + j0 + jl, val);
                }
            }
            __syncthreads();  // before next tile overwrites smem
        }
    }
}

extern "C" void kernel_launch(void* const* d_in, const int* in_sizes, int n_in,
                              void* d_out, int out_size, void* d_ws, size_t ws_size,
                              hipStream_t stream) {
    char* p = (char*)d_ws;
    auto take = [&](size_t bytes) { void* r = p; p += (bytes + 255) & ~(size_t)255; return r; };

    Args a;
    a.xraw = (const unsigned short*)d_in[0];
    a.ei   = (const int*)d_in[1];
    a.deg  = (int*)take(NN * 4);
    a.col  = (int*)take(NN * CAP * 4);
    a.yA   = (float*)take(NN * HD * 4);
    a.yB   = (float*)take(NN * HD * 4);
    a.u    = (float*)take(NN * HD * 4);
    a.v    = (float*)take(NN * HD * 4);
    a.At   = (float*)take(HD * HD * 4);
    a.Bt   = (float*)take(HD * HD * 4);
    a.out  = d_out;

    const int map[13] = {0, 2, 3, 4, 5, 6, 7, 8, 9, 10, 11, 12, 13};
    for (int i = 0; i < 13; i++) {
        int di = map[i];
        a.src[i] = d_in[di];
        a.n[i] = in_sizes[di];
        a.dst[i] = (float*)take((size_t)in_sizes[di] * 4);
    }

    void* params[] = { &a };
    hipLaunchCooperativeKernel((const void*)k_all, dim3(512), dim3(256),
                               params, 0, stream);
}

// Round 8
// 75.163 us; speedup vs baseline: 5.1564x; 5.1564x over previous
//
#include <hip/hip_runtime.h>
#include <hip/hip_bf16.h>

#define NN 1024   // nodes
#define HD 128    // hidden dim
#define NE 32768  // edges
#define CAP 128   // per-row neighbor capacity (Poisson(32): P(>127) ~ 1e-40)

// Device float buffers are fp32 (established R1/R7-NaN vs R2-R6-pass experiment).

// ---- fused: y0 = x @ W0 (blocks 0..1023) + edge fill (1024..1055)
//      + dp_w1 transpose into At/Bt (1056..1119) ----
__global__ __launch_bounds__(128) void k_mm0f(const float* __restrict__ x,
                                              const float* __restrict__ W0,
                                              const int* __restrict__ ei,
                                              const float* __restrict__ dpw1,
                                              int* __restrict__ deg,
                                              int* __restrict__ col,
                                              float* __restrict__ y,
                                              float* __restrict__ At,
                                              float* __restrict__ Bt) {
    int t = threadIdx.x;
    if (blockIdx.x < NN) {
        __shared__ float row[HD];
        int n = blockIdx.x;
        row[t] = x[n * HD + t];
        __syncthreads();
        float acc = 0.f;
#pragma unroll 8
        for (int k = 0; k < HD; k++) acc += row[k] * W0[k * HD + t];
        y[n * HD + t] = acc;   // raw (no dinv)
    } else if (blockIdx.x < NN + 32) {
        int gid = (blockIdx.x - NN) * 128 + t;            // 4096 threads
        for (int e = gid; e < NE; e += 32 * 128) {
            int dst = ei[NE + e];
            int slot = atomicAdd(&deg[dst], 1);
            if (slot < CAP) col[dst * CAP + slot] = ei[e];
        }
    } else {
        int gid = (blockIdx.x - NN - 32) * 128 + t;       // 8192 threads
        for (int i = gid; i < HD * 2 * HD; i += 64 * 128) {
            int h = i >> 8, k = i & 255;                  // dp_w1 [128][256]
            float v = dpw1[i];                            // coalesced read
            if (k < HD) At[k * HD + h] = v;               // scatter write
            else        Bt[(k - HD) * HD + h] = v;
        }
    }
}

// ---- fused: gather(prev raw) -> norm+bias -> relu -> next raw matmul ----
__global__ __launch_bounds__(128) void k_layer(const float* __restrict__ yin,
                                               const int* __restrict__ deg,
                                               const int* __restrict__ col,
                                               const float* __restrict__ bias,
                                               const float* __restrict__ Wnext,
                                               float* __restrict__ yout) {
    __shared__ float hrow[HD];
    int n = blockIdx.x, h = threadIdx.x;
    int cnt = deg[n];
    float dvn = rsqrtf((float)cnt + 1.f);
    float s = dvn * yin[n * HD + h];                       // self-loop
    const int* cp = col + n * CAP;
    for (int i = 0; i < cnt; i++) {
        int c = cp[i];
        s += rsqrtf((float)deg[c] + 1.f) * yin[c * HD + h];
    }
    float hv = dvn * s + bias[h];
    hrow[h] = fmaxf(hv, 0.f);
    __syncthreads();
    float acc = 0.f;
#pragma unroll 8
    for (int k = 0; k < HD; k++) acc += hrow[k] * Wnext[k * HD + h];
    yout[n * HD + h] = acc;   // raw
}

// ---- fused: gather(y2 raw) -> h2 -> emb (fp32 store) -> u,v projections ----
__global__ __launch_bounds__(128) void k_final(const float* __restrict__ yin,
                                               const int* __restrict__ deg,
                                               const int* __restrict__ col,
                                               const float* __restrict__ conv2_b,
                                               const float* __restrict__ out_w,
                                               const float* __restrict__ out_b,
                                               const float* __restrict__ At,
                                               const float* __restrict__ Bt,
                                               const float* __restrict__ dp_b1,
                                               float* __restrict__ emb_out,
                                               float* __restrict__ u,
                                               float* __restrict__ v) {
    __shared__ float h2row[HD];
    __shared__ float embrow[HD];
    int n = blockIdx.x, h = threadIdx.x;
    int cnt = deg[n];
    float dvn = rsqrtf((float)cnt + 1.f);
    float s = dvn * yin[n * HD + h];
    const int* cp = col + n * CAP;
    for (int i = 0; i < cnt; i++) {
        int c = cp[i];
        s += rsqrtf((float)deg[c] + 1.f) * yin[c * HD + h];
    }
    h2row[h] = dvn * s + conv2_b[h];   // no relu on conv2 output
    __syncthreads();
    float acc = out_b[h];
#pragma unroll 8
    for (int k = 0; k < HD; k++) acc += h2row[k] * out_w[k * HD + h];
    embrow[h] = acc;
    emb_out[n * HD + h] = acc;
    __syncthreads();
    float uu = dp_b1[h], vv = 0.f;   // fold dp_b1 into u
#pragma unroll 8
    for (int k = 0; k < HD; k++) {
        float e = embrow[k];
        uu += e * At[k * HD + h];    // coalesced
        vv += e * Bt[k * HD + h];
    }
    u[n * HD + h] = uu;
    v[n * HD + h] = vv;
}

// ---- pairwise: upper-triangle 32x32 tiles, mirrored writes ----
__global__ __launch_bounds__(256) void k_pair(const float* __restrict__ u,
                                              const float* __restrict__ v,
                                              const float* __restrict__ w2,
                                              const float* __restrict__ b2v,
                                              float* __restrict__ dist) {
    __shared__ float4 su4[32 * 32];   // su4[i*32+c] = u[i0+i][4c..4c+3]
    __shared__ float4 sv4[32 * 32];   // sv4[c*32+j] = v[j0+j][4c..4c+3]
    __shared__ float4 sw24[32];
    __shared__ float sp[32][33];

    int t = threadIdx.x;
    int rem = blockIdx.x, bi = 0;
    while (rem >= 32 - bi) { rem -= 32 - bi; bi++; }
    int bj = bi + rem;
    int i0 = bi * 32, j0 = bj * 32;

#pragma unroll
    for (int r = 0; r < 4; r++) {
        int p = t + r * 256;
        int rowp = p >> 5, c = p & 31;
        su4[p] = *(const float4*)(u + (size_t)(i0 + rowp) * HD + (c << 2));
        sv4[c * 32 + rowp] = *(const float4*)(v + (size_t)(j0 + rowp) * HD + (c << 2));
    }
    if (t < 32) sw24[t] = *(const float4*)(w2 + 4 * t);
    __syncthreads();

    int jl = t & 31, ib = t >> 5;
    float acc0 = 0.f, acc1 = 0.f, acc2 = 0.f, acc3 = 0.f;
    for (int c = 0; c < 32; c++) {
        float4 vv = sv4[c * 32 + jl];
        float4 w4 = sw24[c];
        float4 a0 = su4[(ib * 4 + 0) * 32 + c];
        float4 a1 = su4[(ib * 4 + 1) * 32 + c];
        float4 a2 = su4[(ib * 4 + 2) * 32 + c];
        float4 a3 = su4[(ib * 4 + 3) * 32 + c];
        acc0 += fmaxf(a0.x + vv.x, 0.f) * w4.x + fmaxf(a0.y + vv.y, 0.f) * w4.y +
                fmaxf(a0.z + vv.z, 0.f) * w4.z + fmaxf(a0.w + vv.w, 0.f) * w4.w;
        acc1 += fmaxf(a1.x + vv.x, 0.f) * w4.x + fmaxf(a1.y + vv.y, 0.f) * w4.y +
                fmaxf(a1.z + vv.z, 0.f) * w4.z + fmaxf(a1.w + vv.w, 0.f) * w4.w;
        acc2 += fmaxf(a2.x + vv.x, 0.f) * w4.x + fmaxf(a2.y + vv.y, 0.f) * w4.y +
                fmaxf(a2.z + vv.z, 0.f) * w4.z + fmaxf(a2.w + vv.w, 0.f) * w4.w;
        acc3 += fmaxf(a3.x + vv.x, 0.f) * w4.x + fmaxf(a3.y + vv.y, 0.f) * w4.y +
                fmaxf(a3.z + vv.z, 0.f) * w4.z + fmaxf(a3.w + vv.w, 0.f) * w4.w;
    }
    float bb2 = b2v[0];
    float pr0 = 1.f / (1.f + __expf(-(acc0 + bb2)));
    float pr1 = 1.f / (1.f + __expf(-(acc1 + bb2)));
    float pr2 = 1.f / (1.f + __expf(-(acc2 + bb2)));
    float pr3 = 1.f / (1.f + __expf(-(acc3 + bb2)));
    sp[ib * 4 + 0][jl] = pr0;
    sp[ib * 4 + 1][jl] = pr1;
    sp[ib * 4 + 2][jl] = pr2;
    sp[ib * 4 + 3][jl] = pr3;
    __syncthreads();

    if (bi < bj) {
        dist[(size_t)(i0 + ib * 4 + 0) * NN + j0 + jl] = pr0;
        dist[(size_t)(i0 + ib * 4 + 1) * NN + j0 + jl] = pr1;
        dist[(size_t)(i0 + ib * 4 + 2) * NN + j0 + jl] = pr2;
        dist[(size_t)(i0 + ib * 4 + 3) * NN + j0 + jl] = pr3;
#pragma unroll
        for (int p = 0; p < 4; p++) {
            int jrow = ib * 4 + p;
            dist[(size_t)(j0 + jrow) * NN + i0 + jl] = sp[jl][jrow];
        }
    } else {
#pragma unroll
        for (int p = 0; p < 4; p++) {
            int il = ib * 4 + p;
            float val = (il < jl) ? sp[il][jl] : ((il > jl) ? sp[jl][il] : 0.f);
            dist[(size_t)(i0 + il) * NN + j0 + jl] = val;
        }
    }
}

extern "C" void kernel_launch(void* const* d_in, const int* in_sizes, int n_in,
                              void* d_out, int out_size, void* d_ws, size_t ws_size,
                              hipStream_t stream) {
    const float* x    = (const float*)d_in[0];
    const int*   ei   = (const int*)d_in[1];
    const float* w0   = (const float*)d_in[2];
    const float* b0   = (const float*)d_in[3];
    const float* w1   = (const float*)d_in[4];
    const float* b1c  = (const float*)d_in[5];
    const float* w2c  = (const float*)d_in[6];
    const float* b2c  = (const float*)d_in[7];
    const float* ow   = (const float*)d_in[8];
    const float* ob   = (const float*)d_in[9];
    const float* dpw1 = (const float*)d_in[10];
    const float* dpb1 = (const float*)d_in[11];
    const float* dpw2 = (const float*)d_in[12];
    const float* dpb2 = (const float*)d_in[13];

    float* out_emb  = (float*)d_out;
    float* out_dist = out_emb + (size_t)NN * HD;

    char* p = (char*)d_ws;
    auto take = [&](size_t bytes) { void* r = p; p += (bytes + 255) & ~(size_t)255; return r; };
    int*   deg = (int*)take(NN * 4);
    int*   col = (int*)take(NN * CAP * 4);
    float* yA  = (float*)take(NN * HD * 4);
    float* yB  = (float*)take(NN * HD * 4);
    float* u   = (float*)take(NN * HD * 4);
    float* v   = (float*)take(NN * HD * 4);
    float* At  = (float*)take(HD * HD * 4);
    float* Bt  = (float*)take(HD * HD * 4);

    hipMemsetAsync(deg, 0, NN * sizeof(int), stream);
    k_mm0f<<<NN + 96, 128, 0, stream>>>(x, w0, ei, dpw1, deg, col, yA, At, Bt);
    k_layer<<<NN, 128, 0, stream>>>(yA, deg, col, b0, w1, yB);
    k_layer<<<NN, 128, 0, stream>>>(yB, deg, col, b1c, w2c, yA);
    k_final<<<NN, 128, 0, stream>>>(yA, deg, col, b2c, ow, ob, At, Bt, dpb1,
                                    out_emb, u, v);
    k_pair<<<(32 * 33) / 2, 256, 0, stream>>>(u, v, dpw2, dpb2, out_dist);
}

// Round 9
// 74.960 us; speedup vs baseline: 5.1704x; 1.0027x over previous
//
#include <hip/hip_runtime.h>
#include <hip/hip_bf16.h>

#define NN 1024   // nodes
#define HD 128    // hidden dim
#define NE 32768  // edges
#define CAP 128   // per-row neighbor capacity (Poisson(32): P(>127) ~ 1e-40)

// Device float buffers are fp32 (established R1/R7-NaN vs R2-R6-pass experiment).
// NOTE: hipMemsetAsync's fill kernel took ~40us for 4KB inside the graph (R8
// profile) -- use our own zero kernel instead.

__global__ __launch_bounds__(256) void k_zero(int* __restrict__ deg) {
    int t = threadIdx.x;
#pragma unroll
    for (int i = t; i < NN; i += 256) deg[i] = 0;
}

// ---- fused: y0 = x @ W0 raw (blocks 0..1023) + edge fill (1024..1055)
//      + dp_w1 transpose into At/Bt (1056..1119) ----
__global__ __launch_bounds__(128) void k_mm0f(const float* __restrict__ x,
                                              const float* __restrict__ W0,
                                              const int* __restrict__ ei,
                                              const float* __restrict__ dpw1,
                                              int* __restrict__ deg,
                                              int* __restrict__ col,
                                              float* __restrict__ y,
                                              float* __restrict__ At,
                                              float* __restrict__ Bt) {
    int t = threadIdx.x;
    if (blockIdx.x < NN) {
        __shared__ float row[HD];
        int n = blockIdx.x;
        row[t] = x[n * HD + t];
        __syncthreads();
        float acc = 0.f;
#pragma unroll 8
        for (int k = 0; k < HD; k++) acc += row[k] * W0[k * HD + t];
        y[n * HD + t] = acc;   // raw (no dinv; deg not ready yet)
    } else if (blockIdx.x < NN + 32) {
        int gid = (blockIdx.x - NN) * 128 + t;            // 4096 threads
        for (int e = gid; e < NE; e += 32 * 128) {
            int dst = ei[NE + e];
            int slot = atomicAdd(&deg[dst], 1);
            if (slot < CAP) col[dst * CAP + slot] = ei[e];
        }
    } else {
        int gid = (blockIdx.x - NN - 32) * 128 + t;       // 8192 threads
        for (int i = gid; i < HD * 2 * HD; i += 64 * 128) {
            int h = i >> 8, k = i & 255;                  // dp_w1 [128][256]
            float v = dpw1[i];                            // coalesced read
            if (k < HD) At[k * HD + h] = v;               // scatter write
            else        Bt[(k - HD) * HD + h] = v;
        }
    }
}

// ---- layer1: gather RAW y0 (per-neighbor norm) -> relu -> matmul -> SCALED out ----
__global__ __launch_bounds__(128) void k_layer1(const float* __restrict__ yin,
                                                const int* __restrict__ deg,
                                                const int* __restrict__ col,
                                                const float* __restrict__ bias,
                                                const float* __restrict__ Wnext,
                                                float* __restrict__ yout) {
    __shared__ float hrow[HD];
    int n = blockIdx.x, h = threadIdx.x;
    int cnt = deg[n];
    float dvn = rsqrtf((float)cnt + 1.f);
    float s = dvn * yin[n * HD + h];                       // self-loop
    const int* cp = col + n * CAP;
    for (int i = 0; i < cnt; i++) {
        int c = cp[i];
        s += rsqrtf((float)deg[c] + 1.f) * yin[c * HD + h];
    }
    float hv = dvn * s + bias[h];
    hrow[h] = fmaxf(hv, 0.f);
    __syncthreads();
    float acc = 0.f;
#pragma unroll 8
    for (int k = 0; k < HD; k++) acc += hrow[k] * Wnext[k * HD + h];
    yout[n * HD + h] = dvn * acc;   // pre-scaled by own dinv for next gather
}

// ---- layer2: gather SCALED input (plain sum) -> relu -> matmul -> SCALED out ----
__global__ __launch_bounds__(128) void k_layer2(const float* __restrict__ yin,
                                                const int* __restrict__ deg,
                                                const int* __restrict__ col,
                                                const float* __restrict__ bias,
                                                const float* __restrict__ Wnext,
                                                float* __restrict__ yout) {
    __shared__ float hrow[HD];
    int n = blockIdx.x, h = threadIdx.x;
    int cnt = deg[n];
    float dvn = rsqrtf((float)cnt + 1.f);
    float s = yin[n * HD + h];                             // already dinv_n-scaled
    const int* cp = col + n * CAP;
    for (int i = 0; i < cnt; i++) {
        int c = cp[i];
        s += yin[c * HD + h];                              // already dinv_c-scaled
    }
    float hv = dvn * s + bias[h];
    hrow[h] = fmaxf(hv, 0.f);
    __syncthreads();
    float acc = 0.f;
#pragma unroll 8
    for (int k = 0; k < HD; k++) acc += hrow[k] * Wnext[k * HD + h];
    yout[n * HD + h] = dvn * acc;   // pre-scaled
}

// ---- final: gather SCALED y2 -> h2 -> emb (fp32 store) -> u,v projections ----
__global__ __launch_bounds__(128) void k_final(const float* __restrict__ yin,
                                               const int* __restrict__ deg,
                                               const int* __restrict__ col,
                                               const float* __restrict__ conv2_b,
                                               const float* __restrict__ out_w,
                                               const float* __restrict__ out_b,
                                               const float* __restrict__ At,
                                               const float* __restrict__ Bt,
                                               const float* __restrict__ dp_b1,
                                               float* __restrict__ emb_out,
                                               float* __restrict__ u,
                                               float* __restrict__ v) {
    __shared__ float h2row[HD];
    __shared__ float embrow[HD];
    int n = blockIdx.x, h = threadIdx.x;
    int cnt = deg[n];
    float dvn = rsqrtf((float)cnt + 1.f);
    float s = yin[n * HD + h];
    const int* cp = col + n * CAP;
    for (int i = 0; i < cnt; i++) {
        int c = cp[i];
        s += yin[c * HD + h];
    }
    h2row[h] = dvn * s + conv2_b[h];   // no relu on conv2 output
    __syncthreads();
    float acc = out_b[h];
#pragma unroll 8
    for (int k = 0; k < HD; k++) acc += h2row[k] * out_w[k * HD + h];
    embrow[h] = acc;
    emb_out[n * HD + h] = acc;
    __syncthreads();
    float uu = dp_b1[h], vv = 0.f;   // fold dp_b1 into u
#pragma unroll 8
    for (int k = 0; k < HD; k++) {
        float e = embrow[k];
        uu += e * At[k * HD + h];    // coalesced
        vv += e * Bt[k * HD + h];
    }
    u[n * HD + h] = uu;
    v[n * HD + h] = vv;
}

// ---- pairwise: upper-triangle 32x32 tiles, mirrored writes ----
__global__ __launch_bounds__(256) void k_pair(const float* __restrict__ u,
                                              const float* __restrict__ v,
                                              const float* __restrict__ w2,
                                              const float* __restrict__ b2v,
                                              float* __restrict__ dist) {
    __shared__ float4 su4[32 * 32];   // su4[i*32+c] = u[i0+i][4c..4c+3]
    __shared__ float4 sv4[32 * 32];   // sv4[c*32+j] = v[j0+j][4c..4c+3]
    __shared__ float4 sw24[32];
    __shared__ float sp[32][33];

    int t = threadIdx.x;
    int rem = blockIdx.x, bi = 0;
    while (rem >= 32 - bi) { rem -= 32 - bi; bi++; }
    int bj = bi + rem;
    int i0 = bi * 32, j0 = bj * 32;

#pragma unroll
    for (int r = 0; r < 4; r++) {
        int p = t + r * 256;
        int rowp = p >> 5, c = p & 31;
        su4[p] = *(const float4*)(u + (size_t)(i0 + rowp) * HD + (c << 2));
        sv4[c * 32 + rowp] = *(const float4*)(v + (size_t)(j0 + rowp) * HD + (c << 2));
    }
    if (t < 32) sw24[t] = *(const float4*)(w2 + 4 * t);
    __syncthreads();

    int jl = t & 31, ib = t >> 5;
    float acc0 = 0.f, acc1 = 0.f, acc2 = 0.f, acc3 = 0.f;
    for (int c = 0; c < 32; c++) {
        float4 vv = sv4[c * 32 + jl];
        float4 w4 = sw24[c];
        float4 a0 = su4[(ib * 4 + 0) * 32 + c];
        float4 a1 = su4[(ib * 4 + 1) * 32 + c];
        float4 a2 = su4[(ib * 4 + 2) * 32 + c];
        float4 a3 = su4[(ib * 4 + 3) * 32 + c];
        acc0 += fmaxf(a0.x + vv.x, 0.f) * w4.x + fmaxf(a0.y + vv.y, 0.f) * w4.y +
                fmaxf(a0.z + vv.z, 0.f) * w4.z + fmaxf(a0.w + vv.w, 0.f) * w4.w;
        acc1 += fmaxf(a1.x + vv.x, 0.f) * w4.x + fmaxf(a1.y + vv.y, 0.f) * w4.y +
                fmaxf(a1.z + vv.z, 0.f) * w4.z + fmaxf(a1.w + vv.w, 0.f) * w4.w;
        acc2 += fmaxf(a2.x + vv.x, 0.f) * w4.x + fmaxf(a2.y + vv.y, 0.f) * w4.y +
                fmaxf(a2.z + vv.z, 0.f) * w4.z + fmaxf(a2.w + vv.w, 0.f) * w4.w;
        acc3 += fmaxf(a3.x + vv.x, 0.f) * w4.x + fmaxf(a3.y + vv.y, 0.f) * w4.y +
                fmaxf(a3.z + vv.z, 0.f) * w4.z + fmaxf(a3.w + vv.w, 0.f) * w4.w;
    }
    float bb2 = b2v[0];
    float pr0 = 1.f / (1.f + __expf(-(acc0 + bb2)));
    float pr1 = 1.f / (1.f + __expf(-(acc1 + bb2)));
    float pr2 = 1.f / (1.f + __expf(-(acc2 + bb2)));
    float pr3 = 1.f / (1.f + __expf(-(acc3 + bb2)));
    sp[ib * 4 + 0][jl] = pr0;
    sp[ib * 4 + 1][jl] = pr1;
    sp[ib * 4 + 2][jl] = pr2;
    sp[ib * 4 + 3][jl] = pr3;
    __syncthreads();

    if (bi < bj) {
        dist[(size_t)(i0 + ib * 4 + 0) * NN + j0 + jl] = pr0;
        dist[(size_t)(i0 + ib * 4 + 1) * NN + j0 + jl] = pr1;
        dist[(size_t)(i0 + ib * 4 + 2) * NN + j0 + jl] = pr2;
        dist[(size_t)(i0 + ib * 4 + 3) * NN + j0 + jl] = pr3;
#pragma unroll
        for (int p = 0; p < 4; p++) {
            int jrow = ib * 4 + p;
            dist[(size_t)(j0 + jrow) * NN + i0 + jl] = sp[jl][jrow];
        }
    } else {
#pragma unroll
        for (int p = 0; p < 4; p++) {
            int il = ib * 4 + p;
            float val = (il < jl) ? sp[il][jl] : ((il > jl) ? sp[jl][il] : 0.f);
            dist[(size_t)(i0 + il) * NN + j0 + jl] = val;
        }
    }
}

extern "C" void kernel_launch(void* const* d_in, const int* in_sizes, int n_in,
                              void* d_out, int out_size, void* d_ws, size_t ws_size,
                              hipStream_t stream) {
    const float* x    = (const float*)d_in[0];
    const int*   ei   = (const int*)d_in[1];
    const float* w0   = (const float*)d_in[2];
    const float* b0   = (const float*)d_in[3];
    const float* w1   = (const float*)d_in[4];
    const float* b1c  = (const float*)d_in[5];
    const float* w2c  = (const float*)d_in[6];
    const float* b2c  = (const float*)d_in[7];
    const float* ow   = (const float*)d_in[8];
    const float* ob   = (const float*)d_in[9];
    const float* dpw1 = (const float*)d_in[10];
    const float* dpb1 = (const float*)d_in[11];
    const float* dpw2 = (const float*)d_in[12];
    const float* dpb2 = (const float*)d_in[13];

    float* out_emb  = (float*)d_out;
    float* out_dist = out_emb + (size_t)NN * HD;

    char* p = (char*)d_ws;
    auto take = [&](size_t bytes) { void* r = p; p += (bytes + 255) & ~(size_t)255; return r; };
    int*   deg = (int*)take(NN * 4);
    int*   col = (int*)take(NN * CAP * 4);
    float* yA  = (float*)take(NN * HD * 4);
    float* yB  = (float*)take(NN * HD * 4);
    float* u   = (float*)take(NN * HD * 4);
    float* v   = (float*)take(NN * HD * 4);
    float* At  = (float*)take(HD * HD * 4);
    float* Bt  = (float*)take(HD * HD * 4);

    k_zero<<<1, 256, 0, stream>>>(deg);
    k_mm0f<<<NN + 96, 128, 0, stream>>>(x, w0, ei, dpw1, deg, col, yA, At, Bt);
    k_layer1<<<NN, 128, 0, stream>>>(yA, deg, col, b0, w1, yB);
    k_layer2<<<NN, 128, 0, stream>>>(yB, deg, col, b1c, w2c, yA);
    k_final<<<NN, 128, 0, stream>>>(yA, deg, col, b2c, ow, ob, At, Bt, dpb1,
                                    out_emb, u, v);
    k_pair<<<(32 * 33) / 2, 256, 0, stream>>>(u, v, dpw2, dpb2, out_dist);
}

// Round 10
// 62.252 us; speedup vs baseline: 6.2259x; 1.2041x over previous
//
#include <hip/hip_runtime.h>
#include <hip/hip_bf16.h>

#define NN 1024   // nodes
#define HD 128    // hidden dim
#define NE 32768  // edges
#define CAP 128   // per-row neighbor capacity (Poisson(32): P(>127) ~ 1e-40)

// Device float buffers are fp32 (established R1/R7-NaN vs R2-R6-pass experiment).
// Profile lesson (R8/R9): rocprof rows include non-timed dispatches at idle
// clocks -- only dur_us deltas are trustworthy for small kernels.

// ---- k_zero: block 0 zeros deg; blocks 1..64 transpose dp_w1 -> At/Bt ----
__global__ __launch_bounds__(256) void k_zero(int* __restrict__ deg,
                                              const float* __restrict__ dpw1,
                                              float* __restrict__ At,
                                              float* __restrict__ Bt) {
    int t = threadIdx.x;
    if (blockIdx.x == 0) {
#pragma unroll
        for (int i = t; i < NN; i += 256) deg[i] = 0;
    } else {
        int i = (blockIdx.x - 1) * 256 + t;               // 16384 threads
        for (; i < HD * 2 * HD; i += 64 * 256) {
            int h = i >> 8, k = i & 255;                  // dp_w1 [128][256]
            float v = dpw1[i];                            // coalesced read
            if (k < HD) At[k * HD + h] = v;               // scatter write
            else        Bt[(k - HD) * HD + h] = v;
        }
    }
}

// ---- k_mm0f: blocks 0..511: y0 = x@W0 raw, 2 nodes/block; 512..527: edge fill ----
__global__ __launch_bounds__(256) void k_mm0f(const float* __restrict__ x,
                                              const float* __restrict__ W0,
                                              const int* __restrict__ ei,
                                              int* __restrict__ deg,
                                              int* __restrict__ col,
                                              float* __restrict__ y) {
    int t = threadIdx.x;
    if (blockIdx.x < 512) {
        __shared__ float rows[2][HD];
        int half = t >> 7, h = t & 127;
        int n = blockIdx.x * 2 + half;
        rows[half][h] = x[n * HD + h];
        __syncthreads();
        float acc = 0.f;
#pragma unroll 8
        for (int k = 0; k < HD; k++) acc += rows[half][k] * W0[k * HD + h];
        y[n * HD + h] = acc;   // raw (deg not ready yet)
    } else {
        int gid = (blockIdx.x - 512) * 256 + t;           // 4096 threads
        for (int e = gid; e < NE; e += 16 * 256) {
            int dst = ei[NE + e];
            int slot = atomicAdd(&deg[dst], 1);
            if (slot < CAP) col[dst * CAP + slot] = ei[e];
        }
    }
}

// ---- layer1: raw input; LDS dinv table + LDS col staging + ILP gather ----
__global__ __launch_bounds__(256) void k_layer1(const float* __restrict__ yin,
                                                const int* __restrict__ deg,
                                                const int* __restrict__ col,
                                                const float* __restrict__ bias,
                                                const float* __restrict__ W,
                                                float* __restrict__ yout) {
    __shared__ float sdinv[NN];      // 4KB
    __shared__ float hrow[2][HD];
    __shared__ int   scol[2][CAP];
    int t = threadIdx.x;
    int half = t >> 7, h = t & 127;
    int n = blockIdx.x * 2 + half;
    for (int i = t; i < NN; i += 256) sdinv[i] = rsqrtf((float)deg[i] + 1.f);
    int cnt = deg[n];
    if (cnt > CAP) cnt = CAP;
    for (int i = h; i < cnt; i += 128) scol[half][i] = col[n * CAP + i];
    __syncthreads();
    float dvn = sdinv[n];
    float s0 = 0.f, s1 = 0.f, s2 = 0.f, s3 = 0.f;
    int i = 0;
    for (; i + 3 < cnt; i += 4) {
        int c0 = scol[half][i + 0], c1 = scol[half][i + 1];
        int c2 = scol[half][i + 2], c3 = scol[half][i + 3];
        s0 += sdinv[c0] * yin[c0 * HD + h];
        s1 += sdinv[c1] * yin[c1 * HD + h];
        s2 += sdinv[c2] * yin[c2 * HD + h];
        s3 += sdinv[c3] * yin[c3 * HD + h];
    }
    for (; i < cnt; i++) { int c = scol[half][i]; s0 += sdinv[c] * yin[c * HD + h]; }
    float s = dvn * yin[n * HD + h] + ((s0 + s1) + (s2 + s3));
    float hv = dvn * s + bias[h];
    hrow[half][h] = fmaxf(hv, 0.f);
    __syncthreads();
    float acc = 0.f;
#pragma unroll 8
    for (int k = 0; k < HD; k++) acc += hrow[half][k] * W[k * HD + h];
    yout[n * HD + h] = dvn * acc;   // pre-scaled for next gather
}

// ---- layer2: scaled input (plain-sum gather) ----
__global__ __launch_bounds__(256) void k_layer2(const float* __restrict__ yin,
                                                const int* __restrict__ deg,
                                                const int* __restrict__ col,
                                                const float* __restrict__ bias,
                                                const float* __restrict__ W,
                                                float* __restrict__ yout) {
    __shared__ float hrow[2][HD];
    __shared__ int   scol[2][CAP];
    int t = threadIdx.x;
    int half = t >> 7, h = t & 127;
    int n = blockIdx.x * 2 + half;
    int cnt = deg[n];
    if (cnt > CAP) cnt = CAP;
    float dvn = rsqrtf((float)cnt + 1.f);
    for (int i = h; i < cnt; i += 128) scol[half][i] = col[n * CAP + i];
    __syncthreads();
    float s0 = 0.f, s1 = 0.f, s2 = 0.f, s3 = 0.f;
    int i = 0;
    for (; i + 3 < cnt; i += 4) {
        int c0 = scol[half][i + 0], c1 = scol[half][i + 1];
        int c2 = scol[half][i + 2], c3 = scol[half][i + 3];
        s0 += yin[c0 * HD + h];
        s1 += yin[c1 * HD + h];
        s2 += yin[c2 * HD + h];
        s3 += yin[c3 * HD + h];
    }
    for (; i < cnt; i++) s0 += yin[scol[half][i] * HD + h];
    float s = yin[n * HD + h] + ((s0 + s1) + (s2 + s3));
    float hv = dvn * s + bias[h];
    hrow[half][h] = fmaxf(hv, 0.f);
    __syncthreads();
    float acc = 0.f;
#pragma unroll 8
    for (int k = 0; k < HD; k++) acc += hrow[half][k] * W[k * HD + h];
    yout[n * HD + h] = dvn * acc;   // pre-scaled
}

// ---- final: scaled input gather -> h2 -> emb -> u,v ----
__global__ __launch_bounds__(256) void k_final(const float* __restrict__ yin,
                                               const int* __restrict__ deg,
                                               const int* __restrict__ col,
                                               const float* __restrict__ conv2_b,
                                               const float* __restrict__ out_w,
                                               const float* __restrict__ out_b,
                                               const float* __restrict__ At,
                                               const float* __restrict__ Bt,
                                               const float* __restrict__ dp_b1,
                                               float* __restrict__ emb_out,
                                               float* __restrict__ u,
                                               float* __restrict__ v) {
    __shared__ float h2row[2][HD];
    __shared__ float embrow[2][HD];
    __shared__ int   scol[2][CAP];
    int t = threadIdx.x;
    int half = t >> 7, h = t & 127;
    int n = blockIdx.x * 2 + half;
    int cnt = deg[n];
    if (cnt > CAP) cnt = CAP;
    float dvn = rsqrtf((float)cnt + 1.f);
    for (int i = h; i < cnt; i += 128) scol[half][i] = col[n * CAP + i];
    __syncthreads();
    float s0 = 0.f, s1 = 0.f, s2 = 0.f, s3 = 0.f;
    int i = 0;
    for (; i + 3 < cnt; i += 4) {
        int c0 = scol[half][i + 0], c1 = scol[half][i + 1];
        int c2 = scol[half][i + 2], c3 = scol[half][i + 3];
        s0 += yin[c0 * HD + h];
        s1 += yin[c1 * HD + h];
        s2 += yin[c2 * HD + h];
        s3 += yin[c3 * HD + h];
    }
    for (; i < cnt; i++) s0 += yin[scol[half][i] * HD + h];
    float s = yin[n * HD + h] + ((s0 + s1) + (s2 + s3));
    h2row[half][h] = dvn * s + conv2_b[h];   // no relu on conv2 output
    __syncthreads();
    float acc = out_b[h];
#pragma unroll 8
    for (int k = 0; k < HD; k++) acc += h2row[half][k] * out_w[k * HD + h];
    embrow[half][h] = acc;
    emb_out[n * HD + h] = acc;
    __syncthreads();
    float uu = dp_b1[h], vv = 0.f;   // fold dp_b1 into u
#pragma unroll 8
    for (int k = 0; k < HD; k++) {
        float e = embrow[half][k];
        uu += e * At[k * HD + h];    // coalesced
        vv += e * Bt[k * HD + h];
    }
    u[n * HD + h] = uu;
    v[n * HD + h] = vv;
}

// ---- pairwise: upper-triangle 32x32 tiles, mirrored writes ----
__global__ __launch_bounds__(256) void k_pair(const float* __restrict__ u,
                                              const float* __restrict__ v,
                                              const float* __restrict__ w2,
                                              const float* __restrict__ b2v,
                                              float* __restrict__ dist) {
    __shared__ float4 su4[32 * 32];
    __shared__ float4 sv4[32 * 32];
    __shared__ float4 sw24[32];
    __shared__ float sp[32][33];

    int t = threadIdx.x;
    int rem = blockIdx.x, bi = 0;
    while (rem >= 32 - bi) { rem -= 32 - bi; bi++; }
    int bj = bi + rem;
    int i0 = bi * 32, j0 = bj * 32;

#pragma unroll
    for (int r = 0; r < 4; r++) {
        int p = t + r * 256;
        int rowp = p >> 5, c = p & 31;
        su4[p] = *(const float4*)(u + (size_t)(i0 + rowp) * HD + (c << 2));
        sv4[c * 32 + rowp] = *(const float4*)(v + (size_t)(j0 + rowp) * HD + (c << 2));
    }
    if (t < 32) sw24[t] = *(const float4*)(w2 + 4 * t);
    __syncthreads();

    int jl = t & 31, ib = t >> 5;
    float acc0 = 0.f, acc1 = 0.f, acc2 = 0.f, acc3 = 0.f;
    for (int c = 0; c < 32; c++) {
        float4 vv = sv4[c * 32 + jl];
        float4 w4 = sw24[c];
        float4 a0 = su4[(ib * 4 + 0) * 32 + c];
        float4 a1 = su4[(ib * 4 + 1) * 32 + c];
        float4 a2 = su4[(ib * 4 + 2) * 32 + c];
        float4 a3 = su4[(ib * 4 + 3) * 32 + c];
        acc0 += fmaxf(a0.x + vv.x, 0.f) * w4.x + fmaxf(a0.y + vv.y, 0.f) * w4.y +
                fmaxf(a0.z + vv.z, 0.f) * w4.z + fmaxf(a0.w + vv.w, 0.f) * w4.w;
        acc1 += fmaxf(a1.x + vv.x, 0.f) * w4.x + fmaxf(a1.y + vv.y, 0.f) * w4.y +
                fmaxf(a1.z + vv.z, 0.f) * w4.z + fmaxf(a1.w + vv.w, 0.f) * w4.w;
        acc2 += fmaxf(a2.x + vv.x, 0.f) * w4.x + fmaxf(a2.y + vv.y, 0.f) * w4.y +
                fmaxf(a2.z + vv.z, 0.f) * w4.z + fmaxf(a2.w + vv.w, 0.f) * w4.w;
        acc3 += fmaxf(a3.x + vv.x, 0.f) * w4.x + fmaxf(a3.y + vv.y, 0.f) * w4.y +
                fmaxf(a3.z + vv.z, 0.f) * w4.z + fmaxf(a3.w + vv.w, 0.f) * w4.w;
    }
    float bb2 = b2v[0];
    float pr0 = 1.f / (1.f + __expf(-(acc0 + bb2)));
    float pr1 = 1.f / (1.f + __expf(-(acc1 + bb2)));
    float pr2 = 1.f / (1.f + __expf(-(acc2 + bb2)));
    float pr3 = 1.f / (1.f + __expf(-(acc3 + bb2)));
    sp[ib * 4 + 0][jl] = pr0;
    sp[ib * 4 + 1][jl] = pr1;
    sp[ib * 4 + 2][jl] = pr2;
    sp[ib * 4 + 3][jl] = pr3;
    __syncthreads();

    if (bi < bj) {
        dist[(size_t)(i0 + ib * 4 + 0) * NN + j0 + jl] = pr0;
        dist[(size_t)(i0 + ib * 4 + 1) * NN + j0 + jl] = pr1;
        dist[(size_t)(i0 + ib * 4 + 2) * NN + j0 + jl] = pr2;
        dist[(size_t)(i0 + ib * 4 + 3) * NN + j0 + jl] = pr3;
#pragma unroll
        for (int p = 0; p < 4; p++) {
            int jrow = ib * 4 + p;
            dist[(size_t)(j0 + jrow) * NN + i0 + jl] = sp[jl][jrow];
        }
    } else {
#pragma unroll
        for (int p = 0; p < 4; p++) {
            int il = ib * 4 + p;
            float val = (il < jl) ? sp[il][jl] : ((il > jl) ? sp[jl][il] : 0.f);
            dist[(size_t)(i0 + il) * NN + j0 + jl] = val;
        }
    }
}

extern "C" void kernel_launch(void* const* d_in, const int* in_sizes, int n_in,
                              void* d_out, int out_size, void* d_ws, size_t ws_size,
                              hipStream_t stream) {
    const float* x    = (const float*)d_in[0];
    const int*   ei   = (const int*)d_in[1];
    const float* w0   = (const float*)d_in[2];
    const float* b0   = (const float*)d_in[3];
    const float* w1   = (const float*)d_in[4];
    const float* b1c  = (const float*)d_in[5];
    const float* w2c  = (const float*)d_in[6];
    const float* b2c  = (const float*)d_in[7];
    const float* ow   = (const float*)d_in[8];
    const float* ob   = (const float*)d_in[9];
    const float* dpw1 = (const float*)d_in[10];
    const float* dpb1 = (const float*)d_in[11];
    const float* dpw2 = (const float*)d_in[12];
    const float* dpb2 = (const float*)d_in[13];

    float* out_emb  = (float*)d_out;
    float* out_dist = out_emb + (size_t)NN * HD;

    char* p = (char*)d_ws;
    auto take = [&](size_t bytes) { void* r = p; p += (bytes + 255) & ~(size_t)255; return r; };
    int*   deg = (int*)take(NN * 4);
    int*   col = (int*)take(NN * CAP * 4);
    float* yA  = (float*)take(NN * HD * 4);
    float* yB  = (float*)take(NN * HD * 4);
    float* u   = (float*)take(NN * HD * 4);
    float* v   = (float*)take(NN * HD * 4);
    float* At  = (float*)take(HD * HD * 4);
    float* Bt  = (float*)take(HD * HD * 4);

    k_zero<<<65, 256, 0, stream>>>(deg, dpw1, At, Bt);
    k_mm0f<<<528, 256, 0, stream>>>(x, w0, ei, deg, col, yA);
    k_layer1<<<512, 256, 0, stream>>>(yA, deg, col, b0, w1, yB);
    k_layer2<<<512, 256, 0, stream>>>(yB, deg, col, b1c, w2c, yA);
    k_final<<<512, 256, 0, stream>>>(yA, deg, col, b2c, ow, ob, At, Bt, dpb1,
                                     out_emb, u, v);
    k_pair<<<(32 * 33) / 2, 256, 0, stream>>>(u, v, dpw2, dpb2, out_dist);
}